// Round 10
// baseline (114.286 us; speedup 1.0000x reference)
//
#include <hip/hip_runtime.h>

// Poincare contrastive loss, N=4096, D=8, TEMP=0.5.
// sim[i][j] = 1/(1+arcosh(x_ij)), x_ij = 1 + 2*sqdist/((1-sqc_i)(1-sqc_j))
// u = x-1 decomposed as u = A - 4*inv_sel*S,  S = z_i.z_j,
//   A = 2*inv_i*inv_j*(raw_i+raw_j), inv_sel = inv of the SMALLER index side
// e = exp(2*sim) via 368-seg fp16 PWL LUT on u (log2-indexed), built in LDS.
// loss = mean_i -(2*sim[i,partner] - log(sum_{j!=i} e_ij))
//
// HISTORY: LUT -6us; grouped loads -3.5us (r3/r7); fp16 LUT ok; R=4 and
//   cooperative-fusion failed; full-matrix 8/CU kept (1.7x per-pair);
//   occupancy/banks/replication refuted (r1 PMC re-audit: 2.7cy/gather
//   conflict cost only). Plateau: pair ~34us vs ~10us VALU floor across
//   5 structures.
// ROUND-25 (this round): counter-domain decoupling + gather ILP.
//   r9's loop mixes SMEM Q-loads (s_load, OOO retire) with DS gathers in
//   ONE lgkmcnt domain -> every gather wait is lgkmcnt(0), draining the
//   SMEM queue: s_load latency (~200cy, K$ MSHR-limited per CU) serializes
//   with gather latency (~120cy) 16x per wave. Fix:
//   (1) launder q's base pointer into VGPRs (empty asm) -> compiler CANNOT
//       scalarize -> global_load (vmcnt domain, same-addr broadcast, L1);
//       vmcnt independent of lgkmcnt; unroll-2 pipelines groups.
//   (2) batch 8 gathers: all 8 u's -> 8 ds_reads back-to-back -> 8 fma_mix
//       (gather ILP 2 -> 8 outstanding).
//   (3) launch_bounds(256,4): ~92 VGPR budget, 4 waves/SIMD (enough, r3/r5).
// Non-pair fixed: 39.5us harness 256MiB poison-fill - untouchable.

#define D 8
#define QS 12                // padded Q stride (floats) -> 48B, 16B-aligned
#define TWO_N 8192
#define HALF_N 4096
constexpr int BLOCK   = 256;
constexpr int JC      = 64;    // j-columns per block
constexpr int GRP     = 4;     // columns per load-group
constexpr int IBLOCKS = 16;    // 8192 / 512
constexpr int JCHUNKS = 128;   // 8192 / JC
constexpr int NBLK    = IBLOCKS * JCHUNKS;  // 2048
constexpr int NSEG  = 368;   // 23 octaves x 16 segments, u in [2^-16, 2^7)
constexpr int SEG_LO = 1776; // (111 << 4): bits>>19 of u = 2^-16
#define BOUNDARY (1.0f - 1e-5f)
#define LN2   0.6931471805599453f
#define LOG2E 1.4426950408889634f
#define UMIN  1.52587890625e-05f   // 2^-16 -> segment 0
#define UMAX  127.0f               // -> segment 367

typedef float    f32x2 __attribute__((ext_vector_type(2)));
typedef _Float16 f16x2 __attribute__((ext_vector_type(2)));

__device__ __forceinline__ float frcp(float x)  { return __builtin_amdgcn_rcpf(x); }
__device__ __forceinline__ float fsqrt(float x) { return __builtin_amdgcn_sqrtf(x); }
__device__ __forceinline__ float flog2(float x) { return __builtin_amdgcn_logf(x); }
__device__ __forceinline__ float fexp2(float x) { return __builtin_amdgcn_exp2f(x); }
__device__ __forceinline__ f32x2 splat(float v) { return (f32x2){v, v}; }

// pin a pointer to VGPRs so derived loads CANNOT be scalarized to s_load
__device__ __forceinline__ const float* vgpr_ptr(const float* p) {
    asm volatile("" : "+v"(p));
    return p;
}

// DPP wave64 sum: result in lane 63.
__device__ __forceinline__ float dpp_wave_sum(float v) {
    int x;
    x = __builtin_amdgcn_update_dpp(0, __float_as_int(v), 0x111, 0xf, 0xf, false); // row_shr:1
    v += __int_as_float(x);
    x = __builtin_amdgcn_update_dpp(0, __float_as_int(v), 0x112, 0xf, 0xf, false); // row_shr:2
    v += __int_as_float(x);
    x = __builtin_amdgcn_update_dpp(0, __float_as_int(v), 0x114, 0xf, 0xe, false); // row_shr:4
    v += __int_as_float(x);
    x = __builtin_amdgcn_update_dpp(0, __float_as_int(v), 0x118, 0xf, 0xc, false); // row_shr:8
    v += __int_as_float(x);
    x = __builtin_amdgcn_update_dpp(0, __float_as_int(v), 0x142, 0xa, 0xf, false); // row_bcast:15
    v += __int_as_float(x);
    x = __builtin_amdgcn_update_dpp(0, __float_as_int(v), 0x143, 0xc, 0xf, false); // row_bcast:31
    v += __int_as_float(x);
    return v;   // lane 63 = full sum
}

// g(u) = exp(2/(1+arcosh(1+u))), f32 fast-intrinsic eval (LUT node values)
__device__ __forceinline__ float gfun(float u) {
    float y = 1.0f + u + fsqrt(fmaf(u, u, 2.0f * u));
    float d = flog2(y) * LN2;                     // arcosh(1+u)
    return fexp2(2.0f * LOG2E * frcp(1.0f + d));
}

// build the 368-entry fp16 PWL table into LDS (deterministic across blocks)
template<int NTHREADS>
__device__ __forceinline__ void build_stab(f16x2* stab, int tid) {
    for (int e = tid; e < NSEG; e += NTHREADS) {
        const int m0 = e + SEG_LO;
        const int m1 = m0 + 1;
        float ua = __uint_as_float(((unsigned)(m0 >> 4) << 23) | ((unsigned)(m0 & 15) << 19));
        float ub = __uint_as_float(((unsigned)(m1 >> 4) << 23) | ((unsigned)(m1 & 15) << 19));
        float ga = gfun(ua), gb = gfun(ub);
        float sl = (gb - ga) / (ub - ua);
        float ic = fmaf(-sl, ua, ga);
        stab[e] = (f16x2){(_Float16)sl, (_Float16)ic};
    }
}

// e = exp(2*sim) via fp16 PWL pair; caller guarantees u in [UMIN, UMAX]
__device__ __forceinline__ float lut1(float u, const f16x2* __restrict__ tab)
{
    int t = (int)(__float_as_uint(u) >> 19) - SEG_LO;
    f16x2 si = tab[t];
    return fmaf((float)si.x, u, (float)si.y);
}

// MODE: 0 = all j > i, 1 = all j < i, 2 = diagonal overlap
template<int MODE>
__device__ __forceinline__ f32x2 tile_loop(
    const float* __restrict__ qv, const f16x2* __restrict__ stab, int jbase,
    const f32x2* __restrict__ s2, f32x2 t8, f32x2 t9, f32x2 m4,
    int irow0, int irow1)
{
    f32x2 accE = splat(0.0f), accO = splat(0.0f);
    #pragma unroll 2
    for (int g = 0; g < JC / GRP; ++g) {
        // phase 1: group's Q loads - per-lane VGPR addressing (vmcnt domain,
        // same-addr broadcast), pipelined with phase-3 gathers across unroll
        float4 qa[GRP], qb[GRP]; float2 qc2[GRP];
        #pragma unroll
        for (int c = 0; c < GRP; ++c) {
            const float* qp = qv + (size_t)(g * GRP + c) * QS;
            qa[c]  = *(const float4*)(qp);
            qb[c]  = *(const float4*)(qp + 4);
            qc2[c] = *(const float2*)(qp + 8);
        }
        // phase 2: all 8 u's (pure VALU)
        f32x2 u[GRP];
        #pragma unroll
        for (int c = 0; c < GRP; ++c) {
            f32x2 S = splat(0.0f);                             // z_i . z_j
            S = __builtin_elementwise_fma(s2[0], splat(qa[c].x), S);
            S = __builtin_elementwise_fma(s2[1], splat(qa[c].y), S);
            S = __builtin_elementwise_fma(s2[2], splat(qa[c].z), S);
            S = __builtin_elementwise_fma(s2[3], splat(qa[c].w), S);
            S = __builtin_elementwise_fma(s2[4], splat(qb[c].x), S);
            S = __builtin_elementwise_fma(s2[5], splat(qb[c].y), S);
            S = __builtin_elementwise_fma(s2[6], splat(qb[c].z), S);
            S = __builtin_elementwise_fma(s2[7], splat(qb[c].w), S);

            f32x2 A = t8 * splat(qc2[c].x);                    // 2invi*rawi*invj
            A = __builtin_elementwise_fma(t9, splat(qc2[c].y), A);

            f32x2 msel;
            if (MODE == 0) {
                msel = m4;                                     // -4*inv_i
            } else {
                const float nm = -4.0f * qc2[c].x;             // -4*inv_j
                if (MODE == 1) {
                    msel = splat(nm);
                } else {
                    const int j = jbase + g * GRP + c;
                    msel.x = (j > irow0) ? m4.x : nm;
                    msel.y = (j > irow1) ? m4.y : nm;
                }
            }
            f32x2 uu = __builtin_elementwise_fma(S, msel, A);
            uu = __builtin_elementwise_max(uu, splat(UMIN));
            uu = __builtin_elementwise_min(uu, splat(UMAX));
            u[c] = uu;
        }
        // phase 3: 8 gathers issued back-to-back (8-deep lgkmcnt ILP)
        f16x2 sx[GRP], sy[GRP];
        #pragma unroll
        for (int c = 0; c < GRP; ++c) {
            sx[c] = stab[(int)(__float_as_uint(u[c].x) >> 19) - SEG_LO];
            sy[c] = stab[(int)(__float_as_uint(u[c].y) >> 19) - SEG_LO];
        }
        // phase 4: consume
        #pragma unroll
        for (int c = 0; c < GRP; ++c) {
            float ex = fmaf((float)sx[c].x, u[c].x, (float)sx[c].y);
            float ey = fmaf((float)sy[c].x, u[c].y, (float)sy[c].y);
            if (c & 1) { accO.x += ex; accO.y += ey; }
            else       { accE.x += ex; accE.y += ey; }
        }
    }
    return accE + accO;
}

// ---- prep: Q[row] = [z(8), inv, inv*raw, 0, 0]; zero out ----
__global__ __launch_bounds__(256) void prep_kernel(
    const float* __restrict__ zi, const float* __restrict__ zj,
    float* __restrict__ q, float* __restrict__ out)
{
    const int row = blockIdx.x * 256 + threadIdx.x;
    const float* src = (row < HALF_N) ? (zi + (size_t)row * D)
                                      : (zj + (size_t)(row - HALF_N) * D);
    float4 a = *(const float4*)(src);
    float4 b = *(const float4*)(src + 4);
    float raw = a.x*a.x + a.y*a.y + a.z*a.z + a.w*a.w
              + b.x*b.x + b.y*b.y + b.z*b.z + b.w*b.w;
    float inv = frcp(1.0f - fminf(raw, BOUNDARY));
    float* dst = q + (size_t)row * QS;
    *(float4*)(dst)     = a;
    *(float4*)(dst + 4) = b;
    *(float4*)(dst + 8) = make_float4(inv, inv * raw, 0.0f, 0.0f);
    if (row == 0) out[0] = 0.0f;
}

// ---- full-matrix pair kernel: 2048 blocks, vmcnt Q / lgkmcnt LUT ----
__global__ __launch_bounds__(BLOCK, 4) void pair_kernel(
    const float* __restrict__ q, float* __restrict__ part)
{
    __shared__ alignas(16) f16x2 stab[NSEG];   // 1.47 KB fp16 PWL table

    const int tid   = threadIdx.x;
    const int ib    = blockIdx.x >> 7;               // i-block (16)
    const int jc    = blockIdx.x & (JCHUNKS - 1);    // j-chunk (128)
    const int ibase = ib * 512;
    const int jbase = jc * JC;

    build_stab<BLOCK>(stab, tid);

    // own two rows
    const int irow0 = ibase + tid;
    const int irow1 = irow0 + 256;
    f32x2 s2[8], t8, t9, m4;
    {
        const float* q0 = q + (size_t)irow0 * QS;
        const float* q1 = q + (size_t)irow1 * QS;
        float4 a0 = *(const float4*)(q0), b0 = *(const float4*)(q0 + 4);
        float2 c0 = *(const float2*)(q0 + 8);
        float4 a1 = *(const float4*)(q1), b1 = *(const float4*)(q1 + 4);
        float2 c1 = *(const float2*)(q1 + 8);
        s2[0] = (f32x2){a0.x, a1.x}; s2[1] = (f32x2){a0.y, a1.y};
        s2[2] = (f32x2){a0.z, a1.z}; s2[3] = (f32x2){a0.w, a1.w};
        s2[4] = (f32x2){b0.x, b1.x}; s2[5] = (f32x2){b0.y, b1.y};
        s2[6] = (f32x2){b0.z, b1.z}; s2[7] = (f32x2){b0.w, b1.w};
        t8 = (f32x2){2.0f * c0.y, 2.0f * c1.y};   // 2*inv*raw
        t9 = (f32x2){2.0f * c0.x, 2.0f * c1.x};   // 2*inv
        m4 = (f32x2){-4.0f * c0.x, -4.0f * c1.x}; // -4*inv
    }
    __syncthreads();   // stab ready

    // VGPR-pinned base for the j-chunk: forces global_load (vmcnt domain)
    const float* qv = vgpr_ptr(q + (size_t)jbase * QS);

    f32x2 acc;
    if (jbase >= ibase + 512)
        acc = tile_loop<0>(qv, stab, jbase, s2, t8, t9, m4, irow0, irow1);
    else if (jbase + JC <= ibase)
        acc = tile_loop<1>(qv, stab, jbase, s2, t8, t9, m4, irow0, irow1);
    else
        acc = tile_loop<2>(qv, stab, jbase, s2, t8, t9, m4, irow0, irow1);

    // coalesced partial row sums (includes j==i; reduce subtracts it)
    part[(size_t)jc * TWO_N + irow0] = acc.x;
    part[(size_t)jc * TWO_N + irow1] = acc.y;
}

// ---- epilogue: 64 blocks x 128; rowsum from partials, subtract self ----
__global__ __launch_bounds__(128) void reduce_kernel(
    const float* __restrict__ zi, const float* __restrict__ zj,
    const float* __restrict__ part, float* __restrict__ out)
{
    __shared__ alignas(16) f16x2 stab[NSEG];
    __shared__ float swred[2];
    const int tid = threadIdx.x;
    const int i   = blockIdx.x * 128 + tid;

    build_stab<128>(stab, tid);

    // sum the 128 j-chunk partials for this row (coalesced across lanes)
    float rs = 0.0f;
    {
        const float* pp = part + i;
        #pragma unroll 8
        for (int c = 0; c < JCHUNKS; ++c) rs += pp[(size_t)c * TWO_N];
    }

    const int base = (i < HALF_N) ? i : (i - HALF_N);
    const float* pa = (i < HALF_N) ? (zi + (size_t)base * D) : (zj + (size_t)base * D);
    const float* pb = (i < HALF_N) ? (zj + (size_t)base * D) : (zi + (size_t)base * D);
    float4 a0 = *(const float4*)(pa), a1 = *(const float4*)(pa + 4);
    float4 b0 = *(const float4*)(pb), b1 = *(const float4*)(pb + 4);
    float rawa = a0.x*a0.x + a0.y*a0.y + a0.z*a0.z + a0.w*a0.w
               + a1.x*a1.x + a1.y*a1.y + a1.z*a1.z + a1.w*a1.w;
    float rawb = b0.x*b0.x + b0.y*b0.y + b0.z*b0.z + b0.w*b0.w
               + b1.x*b1.x + b1.y*b1.y + b1.z*b1.z + b1.w*b1.w;
    float dot  = a0.x*b0.x + a0.y*b0.y + a0.z*b0.z + a0.w*b0.w
               + a1.x*b1.x + a1.y*b1.y + a1.z*b1.z + a1.w*b1.w;
    float sqd  = fmaxf(rawa + rawb - 2.0f * dot, 0.0f);
    float inva = frcp(1.0f - fminf(rawa, BOUNDARY));
    float invb = frcp(1.0f - fminf(rawb, BOUNDARY));
    float x    = fmaf(2.0f * sqd, inva * invb, 1.0f);
    float t    = fmaf(x, x, -1.0f);
    float s    = fsqrt(fmaxf(t, 0.0f));
    float dist = flog2(x + s) * LN2;
    float sim  = frcp(1.0f + dist);               // positive pair similarity

    __syncthreads();   // stab ready

    // self term, mirroring pair's u = fma(S, -4*inv, A), same clamps + PWL
    float cy = inva * rawa;
    float A  = (2.0f * cy) * inva;
    A = fmaf(2.0f * inva, cy, A);
    float us = fmaf(rawa, -4.0f * inva, A);
    us = fminf(fmaxf(us, UMIN), UMAX);
    float es = lut1(us, stab);

    float denomv = rs - es;
    float dlog = flog2(denomv) * LN2;
    float term = -(2.0f * sim - dlog);

    float ws = dpp_wave_sum(term);
    if ((tid & 63) == 63) swred[tid >> 6] = ws;
    __syncthreads();
    if (tid == 0)
        atomicAdd(out, (swred[0] + swred[1]) * (1.0f / (float)TWO_N));
}

extern "C" void kernel_launch(void* const* d_in, const int* in_sizes, int n_in,
                              void* d_out, int out_size, void* d_ws, size_t ws_size,
                              hipStream_t stream) {
    const float* zi = (const float*)d_in[0];
    const float* zj = (const float*)d_in[1];

    float* q    = (float*)d_ws;                         // [8192 * 12]
    float* part = q + (size_t)TWO_N * QS;               // [128 * 8192] = 4 MB

    prep_kernel<<<TWO_N / 256, 256, 0, stream>>>(zi, zj, q, (float*)d_out);

    pair_kernel<<<NBLK, BLOCK, 0, stream>>>(q, part);

    reduce_kernel<<<TWO_N / 128, 128, 0, stream>>>(zi, zj, part, (float*)d_out);
}

// Round 11
// 103.113 us; speedup vs baseline: 1.1084x; 1.1084x over previous
//
#include <hip/hip_runtime.h>

// Poincare contrastive loss, N=4096, D=8, TEMP=0.5.
// sim[i][j] = 1/(1+arcosh(x_ij)), x_ij = 1 + 2*sqdist/((1-sqc_i)(1-sqc_j))
// For j>i: u = x-1 = A - 4*inv_i*S, S = z_i.z_j, A = 2*inv_i*inv_j*(raw_i+raw_j)
// e = exp(2*sim) via 368-seg fp16 PWL LUT on u (log2-indexed), built in LDS.
// loss = mean_i -(2*sim[i,partner] - log(sum_{j!=i} e_ij))
//
// HISTORY: LUT -6us; grouped scalar loads -3.5us (r3/r7); fp16 LUT ok;
//   R=4, coop-fusion, VGPR-laundered loads all REGRESSED; replication
//   invalid; banks minor (2.7cy/gather).
// KEY r10 MEASUREMENT: pair carries ~23us VALU-busy in BOTH triangle (r1:
//   .58x42) and full-matrix (r10: .39x59) structures; wall = busy/util;
//   r9 ran ~68% util. -> must cut VALU WORK, not stalls.
// ROUND-26 (this round): triangle = half the elements (33.5M vs 67M).
//   e_ij symmetric -> each pair feeds denom[i] (register row acc) AND
//   denom[j] (6-step DPP -> lane-63 global atomic; r1 proved DPP reduce
//   ~free vs alternatives). Strict j>i: self never computed -> reduce
//   needs no LUT/self-cancel; inv_sel==inv_i always -> no MODE selects.
//   1088 tiles (512 rows x 64 cols), r9-quality loop: grouped scalar Q
//   loads (GRP=2), fp16 LDS LUT, 4-phase groups, no colacc array (-32
//   VGPR), launch_bounds(256,4). Model: ~12us VALU + ~3us DPP at 55-65%
//   busy -> pair 22-27us.
// Non-pair fixed: 39.5us harness 256MiB poison-fill - untouchable.

#define D 8
#define QS 12                // padded Q stride (floats) -> 48B, 16B-aligned
#define TWO_N 8192
#define HALF_N 4096
constexpr int BLOCK = 256;
constexpr int JC    = 64;    // j-columns per tile
constexpr int GRP   = 2;     // columns per load-group
constexpr int NTILE = 1088;  // sum_{b=0}^{15} (128 - 8b)
constexpr int NSEG  = 368;   // 23 octaves x 16 segments, u in [2^-16, 2^7)
constexpr int SEG_LO = 1776; // (111 << 4): bits>>19 of u = 2^-16
#define BOUNDARY (1.0f - 1e-5f)
#define LN2   0.6931471805599453f
#define LOG2E 1.4426950408889634f
#define UMIN  1.52587890625e-05f   // 2^-16 -> segment 0
#define UMAX  127.0f               // -> segment 367

typedef float    f32x2 __attribute__((ext_vector_type(2)));
typedef _Float16 f16x2 __attribute__((ext_vector_type(2)));

__device__ __forceinline__ float frcp(float x)  { return __builtin_amdgcn_rcpf(x); }
__device__ __forceinline__ float fsqrt(float x) { return __builtin_amdgcn_sqrtf(x); }
__device__ __forceinline__ float flog2(float x) { return __builtin_amdgcn_logf(x); }
__device__ __forceinline__ float fexp2(float x) { return __builtin_amdgcn_exp2f(x); }
__device__ __forceinline__ f32x2 splat(float v) { return (f32x2){v, v}; }

// DPP wave64 sum: result in lane 63.
__device__ __forceinline__ float dpp_wave_sum(float v) {
    int x;
    x = __builtin_amdgcn_update_dpp(0, __float_as_int(v), 0x111, 0xf, 0xf, false); // row_shr:1
    v += __int_as_float(x);
    x = __builtin_amdgcn_update_dpp(0, __float_as_int(v), 0x112, 0xf, 0xf, false); // row_shr:2
    v += __int_as_float(x);
    x = __builtin_amdgcn_update_dpp(0, __float_as_int(v), 0x114, 0xf, 0xe, false); // row_shr:4
    v += __int_as_float(x);
    x = __builtin_amdgcn_update_dpp(0, __float_as_int(v), 0x118, 0xf, 0xc, false); // row_shr:8
    v += __int_as_float(x);
    x = __builtin_amdgcn_update_dpp(0, __float_as_int(v), 0x142, 0xa, 0xf, false); // row_bcast:15
    v += __int_as_float(x);
    x = __builtin_amdgcn_update_dpp(0, __float_as_int(v), 0x143, 0xc, 0xf, false); // row_bcast:31
    v += __int_as_float(x);
    return v;   // lane 63 = full sum
}

// g(u) = exp(2/(1+arcosh(1+u))), f32 fast-intrinsic eval (LUT node values)
__device__ __forceinline__ float gfun(float u) {
    float y = 1.0f + u + fsqrt(fmaf(u, u, 2.0f * u));
    float d = flog2(y) * LN2;                     // arcosh(1+u)
    return fexp2(2.0f * LOG2E * frcp(1.0f + d));
}

// build the 368-entry fp16 PWL table into LDS
template<int NTHREADS>
__device__ __forceinline__ void build_stab(f16x2* stab, int tid) {
    for (int e = tid; e < NSEG; e += NTHREADS) {
        const int m0 = e + SEG_LO;
        const int m1 = m0 + 1;
        float ua = __uint_as_float(((unsigned)(m0 >> 4) << 23) | ((unsigned)(m0 & 15) << 19));
        float ub = __uint_as_float(((unsigned)(m1 >> 4) << 23) | ((unsigned)(m1 & 15) << 19));
        float ga = gfun(ua), gb = gfun(ub);
        float sl = (gb - ga) / (ub - ua);
        float ic = fmaf(-sl, ua, ga);
        stab[e] = (f16x2){(_Float16)sl, (_Float16)ic};
    }
}

// ---- prep: Q[row] = [z(8), inv, inv*raw, 0, 0]; zero denom + out ----
__global__ __launch_bounds__(256) void prep_kernel(
    const float* __restrict__ zi, const float* __restrict__ zj,
    float* __restrict__ q, float* __restrict__ denom, float* __restrict__ out)
{
    const int row = blockIdx.x * 256 + threadIdx.x;
    const float* src = (row < HALF_N) ? (zi + (size_t)row * D)
                                      : (zj + (size_t)(row - HALF_N) * D);
    float4 a = *(const float4*)(src);
    float4 b = *(const float4*)(src + 4);
    float raw = a.x*a.x + a.y*a.y + a.z*a.z + a.w*a.w
              + b.x*b.x + b.y*b.y + b.z*b.z + b.w*b.w;
    float inv = frcp(1.0f - fminf(raw, BOUNDARY));
    float* dst = q + (size_t)row * QS;
    *(float4*)(dst)     = a;
    *(float4*)(dst + 4) = b;
    *(float4*)(dst + 8) = make_float4(inv, inv * raw, 0.0f, 0.0f);
    denom[row] = 0.0f;
    if (row == 0) out[0] = 0.0f;
}

// ---- triangle pair kernel: 1088 tiles, strict j>i, dual accumulation ----
__global__ __launch_bounds__(BLOCK, 4) void pair_kernel(
    const float* __restrict__ q, float* __restrict__ denom)
{
    __shared__ alignas(16) f16x2 stab[NSEG];   // 1.47 KB fp16 PWL table

    const int tid = threadIdx.x;

    // tile decode: t -> (b = i-block of 512 rows, jbase); F(b)=128b-4b(b-1)
    const int t = blockIdx.x;
    int b = 0;
    #pragma unroll
    for (int k = 1; k < 16; ++k)
        b += (t >= (128 * k - 4 * k * (k - 1))) ? 1 : 0;
    const int Fb    = 128 * b - 4 * b * (b - 1);
    const int ibase = 512 * b;
    const int jcs   = t - Fb;                  // 0 .. 127-8b
    const int jbase = ibase + 64 * jcs;
    const bool diag = (jcs < 8);               // tile overlaps the diagonal

    build_stab<BLOCK>(stab, tid);

    // own two rows
    const int irow0 = ibase + tid;
    const int irow1 = irow0 + 256;
    f32x2 s2[8], t8, t9, m4;
    {
        const float* q0 = q + (size_t)irow0 * QS;
        const float* q1 = q + (size_t)irow1 * QS;
        float4 a0 = *(const float4*)(q0), b0 = *(const float4*)(q0 + 4);
        float2 c0 = *(const float2*)(q0 + 8);
        float4 a1 = *(const float4*)(q1), b1 = *(const float4*)(q1 + 4);
        float2 c1 = *(const float2*)(q1 + 8);
        s2[0] = (f32x2){a0.x, a1.x}; s2[1] = (f32x2){a0.y, a1.y};
        s2[2] = (f32x2){a0.z, a1.z}; s2[3] = (f32x2){a0.w, a1.w};
        s2[4] = (f32x2){b0.x, b1.x}; s2[5] = (f32x2){b0.y, b1.y};
        s2[6] = (f32x2){b0.z, b1.z}; s2[7] = (f32x2){b0.w, b1.w};
        t8 = (f32x2){2.0f * c0.y, 2.0f * c1.y};   // 2*inv*raw
        t9 = (f32x2){2.0f * c0.x, 2.0f * c1.x};   // 2*inv
        m4 = (f32x2){-4.0f * c0.x, -4.0f * c1.x}; // -4*inv (inv_i side: j>i)
    }
    f32x2 accE = splat(0.0f), accO = splat(0.0f);
    __syncthreads();   // stab ready

    const bool l63 = ((tid & 63) == 63);

    #pragma unroll
    for (int gi = 0; gi < JC / GRP; ++gi) {
        const int jj0 = 2 * gi, jj1 = jj0 + 1;

        // phase 1: 2 columns' wave-uniform Q loads (scalarized -> SMEM)
        const float* qp0 = q + (size_t)(jbase + jj0) * QS;
        float4 qa0 = *(const float4*)(qp0);
        float4 qb0 = *(const float4*)(qp0 + 4);
        float2 qc0 = *(const float2*)(qp0 + 8);
        float4 qa1 = *(const float4*)(qp0 + QS);
        float4 qb1 = *(const float4*)(qp0 + QS + 4);
        float2 qc1 = *(const float2*)(qp0 + QS + 8);

        // phase 2: both u's (pure VALU, pk-fp32)
        f32x2 S0 = splat(0.0f), S1 = splat(0.0f);
        S0 = __builtin_elementwise_fma(s2[0], splat(qa0.x), S0);
        S1 = __builtin_elementwise_fma(s2[0], splat(qa1.x), S1);
        S0 = __builtin_elementwise_fma(s2[1], splat(qa0.y), S0);
        S1 = __builtin_elementwise_fma(s2[1], splat(qa1.y), S1);
        S0 = __builtin_elementwise_fma(s2[2], splat(qa0.z), S0);
        S1 = __builtin_elementwise_fma(s2[2], splat(qa1.z), S1);
        S0 = __builtin_elementwise_fma(s2[3], splat(qa0.w), S0);
        S1 = __builtin_elementwise_fma(s2[3], splat(qa1.w), S1);
        S0 = __builtin_elementwise_fma(s2[4], splat(qb0.x), S0);
        S1 = __builtin_elementwise_fma(s2[4], splat(qb1.x), S1);
        S0 = __builtin_elementwise_fma(s2[5], splat(qb0.y), S0);
        S1 = __builtin_elementwise_fma(s2[5], splat(qb1.y), S1);
        S0 = __builtin_elementwise_fma(s2[6], splat(qb0.z), S0);
        S1 = __builtin_elementwise_fma(s2[6], splat(qb1.z), S1);
        S0 = __builtin_elementwise_fma(s2[7], splat(qb0.w), S0);
        S1 = __builtin_elementwise_fma(s2[7], splat(qb1.w), S1);

        f32x2 A0 = t8 * splat(qc0.x);
        f32x2 A1 = t8 * splat(qc1.x);
        A0 = __builtin_elementwise_fma(t9, splat(qc0.y), A0);
        A1 = __builtin_elementwise_fma(t9, splat(qc1.y), A1);

        f32x2 u0 = __builtin_elementwise_fma(S0, m4, A0);
        f32x2 u1 = __builtin_elementwise_fma(S1, m4, A1);
        u0 = __builtin_elementwise_max(u0, splat(UMIN));
        u1 = __builtin_elementwise_max(u1, splat(UMIN));
        u0 = __builtin_elementwise_min(u0, splat(UMAX));
        u1 = __builtin_elementwise_min(u1, splat(UMAX));

        // phase 3: 4 gathers back-to-back
        f16x2 s0x = stab[(int)(__float_as_uint(u0.x) >> 19) - SEG_LO];
        f16x2 s0y = stab[(int)(__float_as_uint(u0.y) >> 19) - SEG_LO];
        f16x2 s1x = stab[(int)(__float_as_uint(u1.x) >> 19) - SEG_LO];
        f16x2 s1y = stab[(int)(__float_as_uint(u1.y) >> 19) - SEG_LO];

        // phase 4: consume
        f32x2 e0 = (f32x2){fmaf((float)s0x.x, u0.x, (float)s0x.y),
                           fmaf((float)s0y.x, u0.y, (float)s0y.y)};
        f32x2 e1 = (f32x2){fmaf((float)s1x.x, u1.x, (float)s1x.y),
                           fmaf((float)s1y.x, u1.y, (float)s1y.y)};

        if (diag) {   // keep strictly j > i (each unordered pair once)
            const int j0 = jbase + jj0, j1 = jbase + jj1;
            e0.x = (j0 > irow0) ? e0.x : 0.0f;
            e0.y = (j0 > irow1) ? e0.y : 0.0f;
            e1.x = (j1 > irow0) ? e1.x : 0.0f;
            e1.y = (j1 > irow1) ? e1.y : 0.0f;
        }
        accE += e0;
        accO += e1;

        // column sums -> lane-63 global atomic (e_ij == e_ji, symmetric)
        float c0 = dpp_wave_sum(e0.x + e0.y);
        float c1 = dpp_wave_sum(e1.x + e1.y);
        if (l63) {
            atomicAdd(&denom[jbase + jj0], c0);
            atomicAdd(&denom[jbase + jj1], c1);
        }
    }

    // row sums
    f32x2 acc2 = accE + accO;
    atomicAdd(&denom[irow0], acc2.x);
    atomicAdd(&denom[irow1], acc2.y);
}

// ---- epilogue: 32 blocks x 256; denom already excludes self; no LUT ----
__global__ __launch_bounds__(256) void reduce_kernel(
    const float* __restrict__ zi, const float* __restrict__ zj,
    const float* __restrict__ denom, float* __restrict__ out)
{
    __shared__ float swred[4];
    const int tid = threadIdx.x;
    const int i   = blockIdx.x * 256 + tid;

    const int base = (i < HALF_N) ? i : (i - HALF_N);
    const float* pa = (i < HALF_N) ? (zi + (size_t)base * D) : (zj + (size_t)base * D);
    const float* pb = (i < HALF_N) ? (zj + (size_t)base * D) : (zi + (size_t)base * D);
    float4 a0 = *(const float4*)(pa), a1 = *(const float4*)(pa + 4);
    float4 b0 = *(const float4*)(pb), b1 = *(const float4*)(pb + 4);
    float rawa = a0.x*a0.x + a0.y*a0.y + a0.z*a0.z + a0.w*a0.w
               + a1.x*a1.x + a1.y*a1.y + a1.z*a1.z + a1.w*a1.w;
    float rawb = b0.x*b0.x + b0.y*b0.y + b0.z*b0.z + b0.w*b0.w
               + b1.x*b1.x + b1.y*b1.y + b1.z*b1.z + b1.w*b1.w;
    float dot  = a0.x*b0.x + a0.y*b0.y + a0.z*b0.z + a0.w*b0.w
               + a1.x*b1.x + a1.y*b1.y + a1.z*b1.z + a1.w*b1.w;
    float sqd  = fmaxf(rawa + rawb - 2.0f * dot, 0.0f);
    float inva = frcp(1.0f - fminf(rawa, BOUNDARY));
    float invb = frcp(1.0f - fminf(rawb, BOUNDARY));
    float x    = fmaf(2.0f * sqd, inva * invb, 1.0f);
    float t    = fmaf(x, x, -1.0f);
    float s    = fsqrt(fmaxf(t, 0.0f));
    float dist = flog2(x + s) * LN2;
    float sim  = frcp(1.0f + dist);               // positive pair similarity
    float dlog = flog2(denom[i]) * LN2;           // self excluded by design
    float term = -(2.0f * sim - dlog);

    float ws = dpp_wave_sum(term);
    if ((tid & 63) == 63) swred[tid >> 6] = ws;
    __syncthreads();
    if (tid == 0)
        atomicAdd(out, (swred[0] + swred[1] + swred[2] + swred[3])
                           * (1.0f / (float)TWO_N));
}

extern "C" void kernel_launch(void* const* d_in, const int* in_sizes, int n_in,
                              void* d_out, int out_size, void* d_ws, size_t ws_size,
                              hipStream_t stream) {
    const float* zi = (const float*)d_in[0];
    const float* zj = (const float*)d_in[1];

    float* denom = (float*)d_ws;                  // [8192]
    float* q     = denom + TWO_N;                 // [8192 * 12]

    prep_kernel<<<TWO_N / 256, 256, 0, stream>>>(zi, zj, q, denom, (float*)d_out);

    pair_kernel<<<NTILE, BLOCK, 0, stream>>>(q, denom);

    reduce_kernel<<<TWO_N / 256, 256, 0, stream>>>(zi, zj, denom, (float*)d_out);
}